// Round 1
// baseline (507.271 us; speedup 1.0000x reference)
//
#include <hip/hip_runtime.h>
#include <hip/hip_bf16.h>

typedef __bf16 bf16x8 __attribute__((ext_vector_type(8)));
typedef float floatx4 __attribute__((ext_vector_type(4)));

#define KDIM 2048
#define MDIM 512
#define HWDIM 4096
#define BM 128
#define BN 128
#define BK 32

__device__ __forceinline__ void g2lds16(const void* g, void* l) {
  __builtin_amdgcn_global_load_lds(
      (const __attribute__((address_space(1))) unsigned int*)g,
      (__attribute__((address_space(3))) unsigned int*)l, 16, 0, 0);
}

// Prologue: Wc[o][c] = (bf16) W[o][c][0][4]   (stride-9 fp32 read, 2MB bf16 write)
__global__ void extract_w_kernel(const float* __restrict__ W, __bf16* __restrict__ Wc) {
  int idx = blockIdx.x * 256 + threadIdx.x;          // 0 .. 512*2048-1
  Wc[idx] = (__bf16)W[(size_t)idx * 9 + 4];
}

// GEMM: out[n][o][hw] = relu( sum_c Wc[o][c] * fea[n][c][hw] + b[o] )
// BM=BN=128, BK=32, 256 threads (4 waves, 2x2), 16x16x32 bf16 MFMA, 4x4 tiles/wave.
__global__ __launch_bounds__(256) void conv1x1_kernel(
    const float* __restrict__ fea, const __bf16* __restrict__ Wc,
    const float* __restrict__ bias, float* __restrict__ out) {
  // As: linear rows of 32 bf16 (64B) — required linear for global_load_lds.
  // Bs: rows of 32 bf16, physical row = row ^ ((row>>3)&1),
  //     16B-granule = g ^ ((row>>1)&3)  -> conflict-free writes AND frag reads.
  __shared__ __align__(16) __bf16 As[BM * BK];
  __shared__ __align__(16) __bf16 Bs[BN * BK];

  const int t    = threadIdx.x;
  const int bx   = blockIdx.x;
  const int mb   = bx & 3;          // M fastest: 4 M-blocks share a fea panel (LLC reuse)
  const int nb   = (bx >> 2) & 31;
  const int img  = bx >> 7;

  const int wave = t >> 6;
  const int lane = t & 63;
  const int l15  = lane & 15;
  const int quad = lane >> 4;
  const int wm   = (wave >> 1) * 64;
  const int wn   = (wave & 1) * 64;

  const float* feaN = fea + (size_t)img * ((size_t)KDIM * HWDIM) + nb * BN;
  float*       outN = out + (size_t)img * ((size_t)MDIM * HWDIM) + nb * BN;

  // ---- B staging geometry (register transpose fp32->bf16) ----
  const int hw2 = t & 63;           // covers hw rows 2*hw2, 2*hw2+1
  const int kg  = wave;             // k-group (8 k's), wave-uniform
  const int r0  = 2 * hw2, r1 = r0 + 1;
  const int p0  = r0 ^ ((r0 >> 3) & 1);
  const int p1  = r1 ^ ((r1 >> 3) & 1);
  const int gsw = (kg ^ (hw2 & 3)) * 8;          // swizzled granule (same both rows)
  __bf16* bdst0 = &Bs[p0 * BK + gsw];
  __bf16* bdst1 = &Bs[p1 * BK + gsw];
  const float* bptr = feaN + (size_t)(kg * 8) * HWDIM + r0;   // running K pointer

  // ---- A staging geometry (global_load_lds, linear) ----
  const __bf16* gA0 = Wc + (size_t)(mb * BM + (t >> 2)) * KDIM + (t & 3) * 8;
  const __bf16* gA1 = gA0 + (size_t)64 * KDIM;
  __bf16* aDst0 = As + t * 8;
  __bf16* aDst1 = As + 2048 + t * 8;

  floatx4 acc[4][4];
#pragma unroll
  for (int i = 0; i < 4; ++i)
#pragma unroll
    for (int j = 0; j < 4; ++j) acc[i][j] = (floatx4){0.f, 0.f, 0.f, 0.f};

  for (int k0 = 0; k0 < KDIM; k0 += BK) {
    // B: 8 coalesced float2 loads (each 512B/wave)
    float2 v[8];
#pragma unroll
    for (int j = 0; j < 8; ++j) v[j] = *(const float2*)(bptr + (size_t)j * HWDIM);

    // A: 2 x 16B direct global->LDS
    g2lds16(gA0 + k0, aDst0);
    g2lds16(gA1 + k0, aDst1);

    // convert + pack + transpose into K-contiguous bf16 rows
    bf16x8 rowa, rowb;
#pragma unroll
    for (int j = 0; j < 8; ++j) { rowa[j] = (__bf16)v[j].x; rowb[j] = (__bf16)v[j].y; }
    *(bf16x8*)bdst0 = rowa;
    *(bf16x8*)bdst1 = rowb;

    __syncthreads();   // drains vmcnt (global_load_lds) + lgkmcnt (ds_write)

    bf16x8 af[4], bf[4];
#pragma unroll
    for (int mt = 0; mt < 4; ++mt) {
      int m = wm + mt * 16 + l15;
      af[mt] = *(const bf16x8*)&As[m * BK + quad * 8];
    }
#pragma unroll
    for (int nt = 0; nt < 4; ++nt) {
      int n  = wn + nt * 16 + l15;
      int pn = n ^ ((n >> 3) & 1);
      int gq = quad ^ ((n >> 1) & 3);
      bf[nt] = *(const bf16x8*)&Bs[pn * BK + gq * 8];
    }
#pragma unroll
    for (int mt = 0; mt < 4; ++mt)
#pragma unroll
      for (int nt = 0; nt < 4; ++nt)
        acc[mt][nt] = __builtin_amdgcn_mfma_f32_16x16x32_bf16(af[mt], bf[nt], acc[mt][nt], 0, 0, 0);

    __syncthreads();   // protect LDS overwrite next iter
    bptr += (size_t)BK * HWDIM;
  }

  // Epilogue: bias + relu, coalesced fp32 stores (lanes 0-15 = consecutive hw)
#pragma unroll
  for (int mt = 0; mt < 4; ++mt) {
#pragma unroll
    for (int r = 0; r < 4; ++r) {
      int o = mb * BM + wm + mt * 16 + quad * 4 + r;
      float bv = bias[o];
      size_t rowoff = (size_t)o * HWDIM;
#pragma unroll
      for (int nt = 0; nt < 4; ++nt) {
        int hw = wn + nt * 16 + l15;
        float x = acc[mt][nt][r] + bv;
        outN[rowoff + hw] = x > 0.f ? x : 0.f;
      }
    }
  }
}

extern "C" void kernel_launch(void* const* d_in, const int* in_sizes, int n_in,
                              void* d_out, int out_size, void* d_ws, size_t ws_size,
                              hipStream_t stream) {
  const float* fea  = (const float*)d_in[0];
  const float* W    = (const float*)d_in[1];
  const float* bias = (const float*)d_in[2];
  float* out = (float*)d_out;
  __bf16* Wc = (__bf16*)d_ws;   // 512*2048*2 = 2MB scratch

  // 512*2048 / 256 = 4096 blocks
  hipLaunchKernelGGL(extract_w_kernel, dim3(4096), dim3(256), 0, stream, W, Wc);
  // grid: 4 (M) * 32 (HW-blocks) * 8 (images) = 1024 blocks
  hipLaunchKernelGGL(conv1x1_kernel, dim3(1024), dim3(256), 0, stream, fea, Wc, bias, out);
}

// Round 2
// 495.449 us; speedup vs baseline: 1.0239x; 1.0239x over previous
//
#include <hip/hip_runtime.h>
#include <hip/hip_bf16.h>

typedef __bf16 bf16x4 __attribute__((ext_vector_type(4)));
typedef __bf16 bf16x8 __attribute__((ext_vector_type(8)));
typedef float floatx4 __attribute__((ext_vector_type(4)));

#define KDIM 2048
#define MDIM 512
#define HWDIM 4096
#define BN 64
#define BK 32
#define NITER (KDIM / BK)   // 64

// Prologue: Wc[o][c] = (bf16) W[o][c][0][4].  4 elems/thread, 8B store.
__global__ void extract_w_kernel(const float* __restrict__ W, __bf16* __restrict__ Wc) {
  int e = (blockIdx.x * 256 + threadIdx.x) * 4;
  bf16x4 h;
#pragma unroll
  for (int j = 0; j < 4; ++j) h[j] = (__bf16)W[(size_t)(e + j) * 9 + 4];
  *(bf16x4*)(Wc + e) = h;
}

// One block = full M (512) x 64-hw panel. 512 threads = 8 waves, wave w owns
// M rows [w*64, w*64+64) x all 64 hw. A direct from L2-resident Wc (no LDS).
// B (shared operand) double-buffered in LDS with conflict-free XOR swizzle.
__global__ __launch_bounds__(512, 4) void conv1x1_kernel(
    const float* __restrict__ fea, const __bf16* __restrict__ Wc,
    const float* __restrict__ bias, float* __restrict__ out) {
  // Bs logical [hw][k] (BK=32 bf16 = 8 granules of 4 bf16 = 8B each).
  // phys granule = logical_granule ^ ((hw>>1)&7)  -> min-cycle writes AND reads.
  __shared__ __align__(16) __bf16 Bs[2][BN * BK];   // 2 x 4 KB

  const int t    = threadIdx.x;
  const int wave = t >> 6;
  const int lane = t & 63;
  const int l15  = lane & 15;
  const int quad = lane >> 4;
  const int wm   = wave * 64;

  const int img = blockIdx.x >> 6;
  const int nb  = blockIdx.x & 63;

  const float* feaN = fea + (size_t)img * KDIM * HWDIM + (size_t)nb * BN;
  float*       outN = out + (size_t)img * MDIM * HWDIM + (size_t)nb * BN;

  // ---- B staging: thread covers hw=lane, k = wave*4 .. wave*4+3 ----
  const int hw   = lane;
  const int kg   = wave;                         // logical granule
  const int boff = hw * BK + (kg ^ ((hw >> 1) & 7)) * 4;  // swizzled elem offset
  const float* bsrc = feaN + (size_t)kg * 4 * HWDIM + hw;

  // ---- A: direct global loads from Wc (L2-hot) ----
  const __bf16* aptr = Wc + (size_t)(wm + l15) * KDIM + quad * 8;

  floatx4 acc[4][4];
#pragma unroll
  for (int i = 0; i < 4; ++i)
#pragma unroll
    for (int j = 0; j < 4; ++j) acc[i][j] = (floatx4){0.f, 0.f, 0.f, 0.f};

  // prologue: stage iter 0 into Bs[0]
  {
    float v[4];
#pragma unroll
    for (int j = 0; j < 4; ++j) v[j] = bsrc[(size_t)j * HWDIM];
    bf16x4 h;
#pragma unroll
    for (int j = 0; j < 4; ++j) h[j] = (__bf16)v[j];
    *(bf16x4*)&Bs[0][boff] = h;
  }
  __syncthreads();

  for (int iter = 0; iter < NITER; ++iter) {
    const int cur = iter & 1;

    // prefetch next B tile into registers (overlaps with MFMA below)
    float vn[4];
    if (iter + 1 < NITER) {
      const float* p = bsrc + (size_t)(iter + 1) * BK * HWDIM;
#pragma unroll
      for (int j = 0; j < 4; ++j) vn[j] = p[(size_t)j * HWDIM];
    }

    // A fragments for this iter (L2 hits)
    bf16x8 af[4];
    const __bf16* ap = aptr + iter * BK;
#pragma unroll
    for (int mt = 0; mt < 4; ++mt)
      af[mt] = *(const bf16x8*)(ap + (size_t)mt * 16 * KDIM);

    // B fragments from LDS (two 8B reads per frag, swizzle-resolved)
    bf16x8 bfr[4];
#pragma unroll
    for (int nt = 0; nt < 4; ++nt) {
      const int n  = nt * 16 + l15;
      const int sw = (n >> 1) & 7;
      const __bf16* row = &Bs[cur][n * BK];
      union { bf16x8 v8; bf16x4 v4[2]; } u;
      u.v4[0] = *(const bf16x4*)(row + ((quad * 2) ^ sw) * 4);
      u.v4[1] = *(const bf16x4*)(row + ((quad * 2 + 1) ^ sw) * 4);
      bfr[nt] = u.v8;
    }

#pragma unroll
    for (int mt = 0; mt < 4; ++mt)
#pragma unroll
      for (int nt = 0; nt < 4; ++nt)
        acc[mt][nt] = __builtin_amdgcn_mfma_f32_16x16x32_bf16(af[mt], bfr[nt], acc[mt][nt], 0, 0, 0);

    // convert + store next B tile into the other buffer
    if (iter + 1 < NITER) {
      bf16x4 hn;
#pragma unroll
      for (int j = 0; j < 4; ++j) hn[j] = (__bf16)vn[j];
      *(bf16x4*)&Bs[cur ^ 1][boff] = hn;
    }
    __syncthreads();
  }

  // Epilogue: bias + relu
#pragma unroll
  for (int mt = 0; mt < 4; ++mt) {
    const int o0 = wm + mt * 16 + quad * 4;
    const float4 bv = *(const float4*)(bias + o0);
    const float bvr[4] = {bv.x, bv.y, bv.z, bv.w};
#pragma unroll
    for (int r = 0; r < 4; ++r) {
      const size_t ro = (size_t)(o0 + r) * HWDIM;
#pragma unroll
      for (int nt = 0; nt < 4; ++nt) {
        float x = acc[mt][nt][r] + bvr[r];
        outN[ro + nt * 16 + l15] = x > 0.f ? x : 0.f;
      }
    }
  }
}

extern "C" void kernel_launch(void* const* d_in, const int* in_sizes, int n_in,
                              void* d_out, int out_size, void* d_ws, size_t ws_size,
                              hipStream_t stream) {
  const float* fea  = (const float*)d_in[0];
  const float* W    = (const float*)d_in[1];
  const float* bias = (const float*)d_in[2];
  float* out = (float*)d_out;
  __bf16* Wc = (__bf16*)d_ws;   // 2 MB scratch

  // 512*2048 elems / 4 per thread / 256 per block = 1024 blocks
  hipLaunchKernelGGL(extract_w_kernel, dim3(1024), dim3(256), 0, stream, W, Wc);
  // 64 hw-panels x 8 images = 512 blocks, 512 threads
  hipLaunchKernelGGL(conv1x1_kernel, dim3(512), dim3(512), 0, stream, fea, Wc, bias, out);
}

// Round 3
// 483.957 us; speedup vs baseline: 1.0482x; 1.0237x over previous
//
#include <hip/hip_runtime.h>
#include <hip/hip_bf16.h>

typedef __bf16 bf16x4 __attribute__((ext_vector_type(4)));
typedef __bf16 bf16x8 __attribute__((ext_vector_type(8)));
typedef float floatx4 __attribute__((ext_vector_type(4)));

#define KDIM 2048
#define MDIM 512
#define HWDIM 4096
#define BN 64
#define BK 32
#define NITER (KDIM / BK)   // 64

// Prologue: Wc[o][c] = (bf16) W[o][c][0][4].
__global__ void extract_w_kernel(const float* __restrict__ W, __bf16* __restrict__ Wc) {
  int e = (blockIdx.x * 256 + threadIdx.x) * 4;
  bf16x4 h;
#pragma unroll
  for (int j = 0; j < 4; ++j) h[j] = (__bf16)W[(size_t)(e + j) * 9 + 4];
  *(bf16x4*)(Wc + e) = h;
}

// One block = full M(512) x 64-hw panel. 8 waves; wave w owns M rows [64w,64w+64).
// A direct from L2-resident Wc. B double-buffered LDS, staged by waves 0-3,
// with depth-2 register prefetch. Swizzle: phys_granule = g ^ ((hw>>1)&3),
// uniform 8 accesses/bank on both ds_write_b128 and ds_read_b128.
__global__ __launch_bounds__(512, 4) void conv1x1_kernel(
    const float* __restrict__ fea, const __bf16* __restrict__ Wc,
    const float* __restrict__ bias, float* __restrict__ out) {
  __shared__ __align__(16) __bf16 Bs[2][BN * BK];   // 2 x 4 KB

  const int t    = threadIdx.x;
  const int wave = t >> 6;
  const int lane = t & 63;
  const int l15  = lane & 15;
  const int quad = lane >> 4;
  const int wm   = wave * 64;

  const int img = blockIdx.x >> 6;
  const int nb  = blockIdx.x & 63;

  const float* feaN = fea + (size_t)img * KDIM * HWDIM + (size_t)nb * BN;
  float*       outN = out + (size_t)img * MDIM * HWDIM + (size_t)nb * BN;

  // ---- B staging (waves 0-3): thread covers hw=lane, k in [8g, 8g+8) ----
  const bool stager = (wave < 4);
  const int  hw   = lane;
  const int  g    = wave & 3;
  const int  boff = hw * BK + ((g ^ ((hw >> 1) & 3)) * 8);   // swizzled elem offset
  const float* bsrc = feaN + (size_t)g * 8 * HWDIM + hw;

  // ---- A: direct global loads from Wc (L2-hot) ----
  const __bf16* aptr = Wc + (size_t)(wm + l15) * KDIM + quad * 8;

  float bpf[2][8];   // depth-2 B prefetch registers
  floatx4 acc[4][4];
#pragma unroll
  for (int i = 0; i < 4; ++i)
#pragma unroll
    for (int j = 0; j < 4; ++j) acc[i][j] = (floatx4){0.f, 0.f, 0.f, 0.f};

  // ---- prologue: issue B(0), B(1); convert+write B(0) ----
  if (stager) {
#pragma unroll
    for (int j = 0; j < 8; ++j) bpf[0][j] = bsrc[(size_t)j * HWDIM];
#pragma unroll
    for (int j = 0; j < 8; ++j) bpf[1][j] = bsrc[(size_t)(BK + j) * HWDIM];
    bf16x8 h0;
#pragma unroll
    for (int j = 0; j < 8; ++j) h0[j] = (__bf16)bpf[0][j];
    *(bf16x8*)&Bs[0][boff] = h0;
  }
  __syncthreads();

  // Body: CUR = i&1 (compile-time). Order matters:
  //  1) A-frag issues FIRST (decoupled from later HBM B issues in vmcnt FIFO)
  //  2) convert+write B(i+1) (its loads are oldest outstanding -> cheap wait)
  //  3) issue B(i+2)
  //  4) ds_read B frags + MFMA
#define KBODY(I, CUR)                                                          \
  {                                                                            \
    const int i_ = (I);                                                        \
    bf16x8 af[4];                                                              \
    const __bf16* ap = aptr + i_ * BK;                                         \
    _Pragma("unroll")                                                          \
    for (int mt = 0; mt < 4; ++mt)                                             \
      af[mt] = *(const bf16x8*)(ap + (size_t)mt * 16 * KDIM);                  \
    if (stager && i_ + 1 < NITER) {                                            \
      bf16x8 hn;                                                               \
      _Pragma("unroll")                                                        \
      for (int j = 0; j < 8; ++j) hn[j] = (__bf16)bpf[(CUR) ^ 1][j];           \
      *(bf16x8*)&Bs[(CUR) ^ 1][boff] = hn;                                     \
    }                                                                          \
    if (stager && i_ + 2 < NITER) {                                            \
      const float* p = bsrc + (size_t)(i_ + 2) * BK * HWDIM;                   \
      _Pragma("unroll")                                                        \
      for (int j = 0; j < 8; ++j) bpf[(CUR)][j] = p[(size_t)j * HWDIM];        \
    }                                                                          \
    _Pragma("unroll")                                                          \
    for (int nt = 0; nt < 4; ++nt) {                                           \
      const int n_ = nt * 16 + l15;                                            \
      const bf16x8 bfr =                                                       \
          *(const bf16x8*)&Bs[(CUR)][n_ * BK + ((quad ^ ((n_ >> 1) & 3)) * 8)];\
      _Pragma("unroll")                                                        \
      for (int mt = 0; mt < 4; ++mt)                                           \
        acc[mt][nt] = __builtin_amdgcn_mfma_f32_16x16x32_bf16(af[mt], bfr,     \
                                                              acc[mt][nt],    \
                                                              0, 0, 0);       \
    }                                                                          \
    __syncthreads();                                                           \
  }

  for (int i = 0; i < NITER; i += 2) {
    KBODY(i, 0)
    KBODY(i + 1, 1)
  }
#undef KBODY

  // Epilogue: bias + relu  (C/D: col = l15, row = quad*4 + r  — verified in R1/R2)
#pragma unroll
  for (int mt = 0; mt < 4; ++mt) {
    const int o0 = wm + mt * 16 + quad * 4;
    const float4 bv = *(const float4*)(bias + o0);
    const float bvr[4] = {bv.x, bv.y, bv.z, bv.w};
#pragma unroll
    for (int r = 0; r < 4; ++r) {
      const size_t ro = (size_t)(o0 + r) * HWDIM;
#pragma unroll
      for (int nt = 0; nt < 4; ++nt) {
        float x = acc[mt][nt][r] + bvr[r];
        outN[ro + nt * 16 + l15] = x > 0.f ? x : 0.f;
      }
    }
  }
}

extern "C" void kernel_launch(void* const* d_in, const int* in_sizes, int n_in,
                              void* d_out, int out_size, void* d_ws, size_t ws_size,
                              hipStream_t stream) {
  const float* fea  = (const float*)d_in[0];
  const float* W    = (const float*)d_in[1];
  const float* bias = (const float*)d_in[2];
  float* out = (float*)d_out;
  __bf16* Wc = (__bf16*)d_ws;   // 2 MB scratch

  hipLaunchKernelGGL(extract_w_kernel, dim3(1024), dim3(256), 0, stream, W, Wc);
  hipLaunchKernelGGL(conv1x1_kernel, dim3(512), dim3(512), 0, stream, fea, Wc, bias, out);
}